// Round 1
// baseline (125.119 us; speedup 1.0000x reference)
//
#include <hip/hip_runtime.h>
#include <cstdint>

#define NTOK 65536
#define DIM 240
#define KP 256

typedef short bf16x8 __attribute__((ext_vector_type(8)));
typedef float f32x16 __attribute__((ext_vector_type(16)));

union U16B { uint4 u; bf16x8 v; };

__device__ __forceinline__ unsigned short f2bf(float x) {
  unsigned int u = __float_as_uint(x);
  u += 0x7fffu + ((u >> 16) & 1u);     // RNE
  return (unsigned short)(u >> 16);
}

// ---------------- kernel 1: pack expert weights to bf16 [8][256][256], bias fused at k=240
__global__ __launch_bounds__(256) void prep_w(const float* __restrict__ ew,
                                              const float* __restrict__ eb,
                                              unsigned short* __restrict__ Wb) {
  int idx = blockIdx.x * 256 + threadIdx.x;     // 131072 threads, 4 k's each
  int k0 = (idx & 63) << 2;
  int n  = (idx >> 6) & 255;
  int e  = idx >> 14;
  ushort4 v = {0, 0, 0, 0};
  if (n < DIM) {
    float f0 = 0.f, f1 = 0.f, f2 = 0.f, f3 = 0.f;
    const float* wrow = ew + (e * DIM + n) * DIM;
    if (k0 < DIM) { f0 = wrow[k0]; f1 = wrow[k0 + 1]; f2 = wrow[k0 + 2]; f3 = wrow[k0 + 3]; }
    else if (k0 == DIM) { f0 = eb[e * DIM + n]; }   // bias column
    v.x = f2bf(f0); v.y = f2bf(f1); v.z = f2bf(f2); v.w = f2bf(f3);
  }
  *(ushort4*)&Wb[(size_t)idx * 4] = v;
}

// ---------------- kernel 2: gating (one wave per token) + x -> bf16 padded [NTOK][256]
__global__ __launch_bounds__(256) void gating(const float* __restrict__ x,
                                              const float* __restrict__ gw,
                                              const float* __restrict__ gb,
                                              unsigned short* __restrict__ xbp,
                                              float* __restrict__ cw) {
  __shared__ __align__(16) float gwT[8 * DIM];
  for (int i = threadIdx.x; i < 8 * DIM; i += 256) gwT[(i & 7) * DIM + (i >> 3)] = gw[i];
  __syncthreads();
  const int lane = threadIdx.x & 63;
  const int wav = (blockIdx.x << 2) + (threadIdx.x >> 6);   // 16384 waves
  float gbv[8];
#pragma unroll
  for (int e = 0; e < 8; ++e) gbv[e] = gb[e];
  for (int t = wav; t < NTOK; t += 16384) {
    float p[8];
#pragma unroll
    for (int e = 0; e < 8; ++e) p[e] = 0.f;
    float4 xv = make_float4(0.f, 0.f, 0.f, 0.f);
    if (lane < 60) {
      xv = *(const float4*)(x + (size_t)t * DIM + lane * 4);
#pragma unroll
      for (int e = 0; e < 8; ++e) {
        const float4 g = *(const float4*)(gwT + e * DIM + lane * 4);
        p[e] += xv.x * g.x + xv.y * g.y + xv.z * g.z + xv.w * g.w;
      }
    }
#pragma unroll
    for (int m = 1; m < 64; m <<= 1) {
#pragma unroll
      for (int e = 0; e < 8; ++e) p[e] += __shfl_xor(p[e], m, 64);
    }
    float l[8];
#pragma unroll
    for (int e = 0; e < 8; ++e) l[e] = p[e] + gbv[e];
    int i1 = 0; float b1 = l[0];
#pragma unroll
    for (int e = 1; e < 8; ++e) if (l[e] > b1) { b1 = l[e]; i1 = e; }
    int i2 = -1; float b2 = -3.0e38f;
#pragma unroll
    for (int e = 0; e < 8; ++e) if (e != i1 && l[e] > b2) { b2 = l[e]; i2 = e; }
    // top-2 softmax renorm: w1 = 1/(1+exp(l2-l1))
    float q = expf(b2 - b1);
    float w1 = 1.f / (1.f + q);
    float w2 = q / (1.f + q);
    ushort4 v = {0, 0, 0, 0};
    if (lane < 60) { v.x = f2bf(xv.x); v.y = f2bf(xv.y); v.z = f2bf(xv.z); v.w = f2bf(xv.w); }
    else if (lane == 60) v.x = 0x3F80;          // x[240] = 1.0 (bias column)
    *(ushort4*)(xbp + (size_t)t * KP + lane * 4) = v;
    if (lane < 8) cw[(size_t)t * 8 + lane] = (lane == i1) ? w1 : ((lane == i2) ? w2 : 0.f);
  }
}

// ---------------- kernel 3: fused dense-weighted MoE GEMM
#define GLDS16(g, l)                                                        \
  __builtin_amdgcn_global_load_lds(                                         \
      (__attribute__((address_space(1))) unsigned int*)(g),                 \
      (__attribute__((address_space(3))) unsigned int*)(l), 16, 0, 0)

// stage one [256 rows][64 k] bf16 chunk (32 KB) from a [256][256] bf16 matrix.
// LDS linear; global source pre-XOR'd so ds_read side can use byte ^= ((row&7)<<4).
__device__ __forceinline__ void stage_tile(const unsigned short* gbase, char* lds,
                                           int kc, int wid, int lane) {
  const char* g = (const char*)gbase;
#pragma unroll
  for (int j = 0; j < 4; ++j) {
    const int o = ((wid * 4 + j) << 10) + lane * 16;
    const int r = o >> 7;           // LDS/global row
    const int b = o & 127;          // byte within 128B row slice
    GLDS16(g + (size_t)r * 512 + kc * 128 + (b ^ ((r & 7) << 4)),
           lds + ((wid * 4 + j) << 10));
  }
}

__device__ __forceinline__ bf16x8 scale_frag(uint4 raw, float w) {
  unsigned int r[4] = {raw.x, raw.y, raw.z, raw.w};
  unsigned int o[4];
#pragma unroll
  for (int i = 0; i < 4; ++i) {
    float lo = __uint_as_float(r[i] << 16) * w;
    float hi = __uint_as_float(r[i] & 0xffff0000u) * w;
    unsigned int pk;
    asm("v_cvt_pk_bf16_f32 %0, %1, %2" : "=v"(pk) : "v"(lo), "v"(hi));
    o[i] = pk;
  }
  U16B u; u.u = make_uint4(o[0], o[1], o[2], o[3]);
  return u.v;
}

__global__ __launch_bounds__(512, 2) void moe_gemm(const unsigned short* __restrict__ xbp,
                                                   const unsigned short* __restrict__ Wb,
                                                   const float* __restrict__ cwg,
                                                   float* __restrict__ out) {
  extern __shared__ __align__(16) char smem[];
  char* xb = smem;                         // [2][32768] x chunks
  char* bb = smem + 65536;                 // [2][32768] W chunks
  float* cwl = (float*)(smem + 131072);    // [256][8] combine weights

  const int tid = threadIdx.x;
  const int wid = tid >> 6, lane = tid & 63;
  const int wr = wid >> 1, wc = wid & 1;   // 4 row-waves x 2 col-waves
  const int l31 = lane & 31;
  const size_t row0 = (size_t)blockIdx.x * 256;

  *(float4*)(cwl + tid * 4) = *(const float4*)(cwg + row0 * 8 + tid * 4);

  const unsigned short* xg = xbp + row0 * KP;

  stage_tile(xg, xb, 0, wid, lane);
  stage_tile(Wb, bb, 0, wid, lane);
  __syncthreads();                          // drains vmcnt

  f32x16 acc[2][4] = {};

  for (int i = 0; i < 32; ++i) {            // i = kc*8 + e
    const int kc = i >> 3, e = i & 7;
    const int nx = i + 1;
    if (nx < 32) {
      const int kcn = nx >> 3, en = nx & 7;
      if (en == 0) stage_tile(xg, xb + ((kcn & 1) << 15), kcn, wid, lane);
      stage_tile(Wb + (size_t)en * 65536, bb + ((nx & 1) << 15), kcn, wid, lane);
    }
    const char* xc = xb + ((kc & 1) << 15);
    const char* bc = bb + ((i & 1) << 15);
    const float w0 = cwl[(wr * 64 + l31) * 8 + e];
    const float w1 = cwl[(wr * 64 + 32 + l31) * 8 + e];
#pragma unroll
    for (int ks = 0; ks < 4; ++ks) {
      const int sx = (ks * 32 + ((lane >> 5) << 4)) ^ ((lane & 7) << 4);
      bf16x8 a0 = scale_frag(*(const uint4*)(xc + ((wr * 64 + l31) << 7) + sx), w0);
      bf16x8 a1 = scale_frag(*(const uint4*)(xc + ((wr * 64 + 32 + l31) << 7) + sx), w1);
#pragma unroll
      for (int cf = 0; cf < 4; ++cf) {
        U16B ub; ub.u = *(const uint4*)(bc + ((wc * 128 + cf * 32 + l31) << 7) + sx);
        acc[0][cf] = __builtin_amdgcn_mfma_f32_32x32x16_bf16(a0, ub.v, acc[0][cf], 0, 0, 0);
        acc[1][cf] = __builtin_amdgcn_mfma_f32_32x32x16_bf16(a1, ub.v, acc[1][cf], 0, 0, 0);
      }
    }
    __syncthreads();                        // next-chunk loads drained + bufs released
  }

#pragma unroll
  for (int cf = 0; cf < 4; ++cf) {
    const int col = wc * 128 + cf * 32 + l31;
    if (col < DIM) {
#pragma unroll
      for (int rf = 0; rf < 2; ++rf) {
#pragma unroll
        for (int r = 0; r < 16; ++r) {
          const int rw = wr * 64 + rf * 32 + (r & 3) + ((r >> 2) << 3) + ((lane >> 5) << 2);
          out[(row0 + rw) * DIM + col] = acc[rf][cf][r];
        }
      }
    }
  }
}

extern "C" void kernel_launch(void* const* d_in, const int* in_sizes, int n_in,
                              void* d_out, int out_size, void* d_ws, size_t ws_size,
                              hipStream_t stream) {
  const float* x  = (const float*)d_in[0];
  const float* gw = (const float*)d_in[1];
  const float* gb = (const float*)d_in[2];
  const float* ew = (const float*)d_in[3];
  const float* eb = (const float*)d_in[4];
  float* out = (float*)d_out;

  // workspace layout: Wb bf16 [8][256][256] (1 MB) | xbp bf16 [65536][256] (32 MB) | cw f32 [65536][8] (2 MB)
  unsigned short* Wb  = (unsigned short*)d_ws;
  unsigned short* xbp = (unsigned short*)((char*)d_ws + (1u << 20));
  float* cw = (float*)((char*)d_ws + (1u << 20) + (size_t)NTOK * KP * 2);

  hipFuncSetAttribute((const void*)moe_gemm, hipFuncAttributeMaxDynamicSharedMemorySize, 139264);

  prep_w<<<512, 256, 0, stream>>>(ew, eb, Wb);
  gating<<<4096, 256, 0, stream>>>(x, gw, gb, xbp, cw);
  moe_gemm<<<256, 512, 139264, stream>>>(xbp, Wb, cw, out);
}